// Round 1
// baseline (190.392 us; speedup 1.0000x reference)
//
#include <hip/hip_runtime.h>
#include <cstdint>
#include <cstddef>

typedef __attribute__((ext_vector_type(8))) short short8;
typedef __attribute__((ext_vector_type(4))) float floatx4;

typedef __attribute__((address_space(1))) const void gvoid_t;
typedef __attribute__((address_space(3))) void lvoid_t;

// fp32 -> bf16 with round-to-nearest-even (bit pattern as short)
__device__ inline short f2bf(float f) {
    unsigned u = __float_as_uint(f);
    u = (u + 0x7FFFu + ((u >> 16) & 1u)) >> 16;
    return (short)u;
}

// ---------------------------------------------------------------------------
// Kernel 1: convert x (fp32 [M][K]) -> bf16 [M][K] in workspace
// ---------------------------------------------------------------------------
__global__ __launch_bounds__(256) void convert_x_kernel(
    const float* __restrict__ x, short* __restrict__ xb, long long n)
{
    long long i = ((long long)blockIdx.x * 256 + threadIdx.x) * 8;
    if (i + 8 > n) return;
    const float4* p = (const float4*)(x + i);
    float4 v0 = p[0];
    float4 v1 = p[1];
    short8 h;
    h[0] = f2bf(v0.x); h[1] = f2bf(v0.y); h[2] = f2bf(v0.z); h[3] = f2bf(v0.w);
    h[4] = f2bf(v1.x); h[5] = f2bf(v1.y); h[6] = f2bf(v1.z); h[7] = f2bf(v1.w);
    *(short8*)(xb + i) = h;
}

// ---------------------------------------------------------------------------
// Kernel 2: dequantize qweight (int32 [K/8][N], 8x4-bit packed along K) into
// transposed bf16 deqT [N][K] (K contiguous) so the GEMM can read B-fragments
// as contiguous k-runs.
// Tile: 32 qweight rows (256 k) x 64 n per block; LDS transpose, pad 65.
// ---------------------------------------------------------------------------
__global__ __launch_bounds__(256) void dequant_kernel(
    const int* __restrict__ qw, const float* __restrict__ scales,
    const float* __restrict__ zps, short* __restrict__ deqT,
    int N, int K)
{
    __shared__ int lds_q[32 * 65];
    const int t  = threadIdx.x;
    const int n0 = blockIdx.x * 64;
    const int r0 = blockIdx.y * 32;   // qweight row tile (32 rows = 256 k)

    // Phase 1: coalesced load of the 32x64 int32 tile into LDS (pad 65)
    #pragma unroll
    for (int v = 0; v < 2; ++v) {
        int idx = t + v * 256;            // 0..511 int4-chunks
        int row = idx >> 4;               // 16 int4 per 64-col row
        int c4  = (idx & 15) * 4;
        const int4 q4 = *(const int4*)(qw + (size_t)(r0 + row) * N + n0 + c4);
        int base = row * 65 + c4;
        lds_q[base + 0] = q4.x;
        lds_q[base + 1] = q4.y;
        lds_q[base + 2] = q4.z;
        lds_q[base + 3] = q4.w;
    }
    __syncthreads();

    // Phase 2: thread owns (n = t>>2, 8 qweight rows = 64 contiguous k)
    const int nl = t >> 2;
    const int rc = (t & 3) * 8;
    // k-range [(r0+rc)*8, +64) lies inside one 128-group:
    const int g  = (r0 >> 4) + ((t & 3) >> 1);

    float s = scales[(size_t)g * N + n0 + nl];
    s = fminf(fmaxf(s, 1e-5f), 1e4f);
    float z = rintf(zps[(size_t)g * N + n0 + nl]);   // round-half-even like jnp.round
    z = fminf(fmaxf(z, 0.0f), 15.0f);

    short* outp = deqT + (size_t)(n0 + nl) * K + (size_t)(r0 + rc) * 8;
    #pragma unroll
    for (int i = 0; i < 8; ++i) {
        int q = lds_q[(rc + i) * 65 + nl];
        short8 h;
        #pragma unroll
        for (int j = 0; j < 8; ++j) {
            float f = (float)((q >> (4 * j)) & 15);
            h[j] = f2bf((f - z) * s);
        }
        *(short8*)(outp + i * 8) = h;   // 16B contiguous per thread
    }
}

// ---------------------------------------------------------------------------
// Kernel 3: bf16 GEMM, C = A[M][K] * Bt[N][K]^T + bias, fp32 out.
// m97 structure: 128x128 tile, BK=64, global_load_lds(16B) staging,
// 4 waves each computing 64x64 via 4x4 grid of 16x16x32 MFMA.
// XOR chunk swizzle: LDS position p of row m holds global chunk p^(m&7),
// so fragment ds_read_b128s spread over all 32 banks (2-way only).
// ---------------------------------------------------------------------------
#define BM 128
#define BN 128
#define BK 64

__global__ __launch_bounds__(256) void gemm_bf16_bt(
    const short* __restrict__ A, const short* __restrict__ Bt,
    const float* __restrict__ bias, float* __restrict__ C,
    int M, int N, int K)
{
    __shared__ __align__(16) short a_lds[BM * BK];
    __shared__ __align__(16) short b_lds[BN * BK];

    const int t  = threadIdx.x;
    const int L  = t & 63;
    const int w  = t >> 6;
    const int m0 = blockIdx.y * BM;
    const int n0 = blockIdx.x * BN;
    const int wm = (w & 1) * 64;
    const int wn = (w >> 1) * 64;

    floatx4 acc[4][4] = {};

    // staging: per inst i, wave w covers rows i*32 + w*8 + (L>>3);
    // LDS slot = uniform base + lane*16B  (hardware-enforced order)
    const int sr = L >> 3;           // row within the wave's 8-row chunk
    const int sc = L & 7;            // LDS 16B-chunk position within row
    const int gc = sc ^ sr;          // swizzled global chunk ((row&7)==sr)
    const short* ag = A  + (size_t)(m0 + w * 8 + sr) * K + gc * 8;
    const short* bg = Bt + (size_t)(n0 + w * 8 + sr) * K + gc * 8;
    short* a_dst = a_lds + (w * 8) * BK;
    short* b_dst = b_lds + (w * 8) * BK;

    for (int kt = 0; kt < K; kt += BK) {
        #pragma unroll
        for (int i = 0; i < 4; ++i) {
            __builtin_amdgcn_global_load_lds(
                (gvoid_t*)(ag + (size_t)i * 32 * K + kt),
                (lvoid_t*)(a_dst + i * 32 * BK), 16, 0, 0);
            __builtin_amdgcn_global_load_lds(
                (gvoid_t*)(bg + (size_t)i * 32 * K + kt),
                (lvoid_t*)(b_dst + i * 32 * BK), 16, 0, 0);
        }
        __syncthreads();

        #pragma unroll
        for (int s = 0; s < 2; ++s) {
            const int p = ((s * 4) + (L >> 4)) ^ (L & 7);  // swizzled LDS chunk
            short8 af[4], bfr[4];
            #pragma unroll
            for (int i = 0; i < 4; ++i)
                af[i] = *(const short8*)(a_lds + (wm + 16 * i + (L & 15)) * BK + p * 8);
            #pragma unroll
            for (int j = 0; j < 4; ++j)
                bfr[j] = *(const short8*)(b_lds + (wn + 16 * j + (L & 15)) * BK + p * 8);
            #pragma unroll
            for (int i = 0; i < 4; ++i) {
                #pragma unroll
                for (int j = 0; j < 4; ++j)
                    acc[i][j] = __builtin_amdgcn_mfma_f32_16x16x32_bf16(
                        af[i], bfr[j], acc[i][j], 0, 0, 0);
            }
        }
        __syncthreads();
    }

    // Epilogue: C/D layout col = lane&15, row = (lane>>4)*4 + reg  (m89/m91)
    float bv[4];
    #pragma unroll
    for (int j = 0; j < 4; ++j)
        bv[j] = bias[n0 + wn + 16 * j + (L & 15)];
    const int col0 = n0 + wn + (L & 15);
    #pragma unroll
    for (int i = 0; i < 4; ++i) {
        const int row0 = m0 + wm + 16 * i + (L >> 4) * 4;
        #pragma unroll
        for (int r = 0; r < 4; ++r) {
            float* outr = C + (size_t)(row0 + r) * N + col0;
            #pragma unroll
            for (int j = 0; j < 4; ++j)
                outr[16 * j] = acc[i][j][r] + bv[j];
        }
    }
}

// ---------------------------------------------------------------------------
extern "C" void kernel_launch(void* const* d_in, const int* in_sizes, int n_in,
                              void* d_out, int out_size, void* d_ws, size_t ws_size,
                              hipStream_t stream)
{
    const float* x      = (const float*)d_in[0];
    const float* scales = (const float*)d_in[1];
    const float* zps    = (const float*)d_in[2];
    const float* bias   = (const float*)d_in[3];
    const int*   qw     = (const int*)d_in[4];

    const int N = in_sizes[3];          // outfeatures (bias length)
    const int G = in_sizes[1] / N;      // num groups
    const int K = G * 128;              // infeatures
    const int M = in_sizes[0] / K;      // tokens

    short* xb   = (short*)d_ws;                       // M*K bf16
    short* deqT = xb + (size_t)M * K;                 // N*K bf16
    float* out  = (float*)d_out;

    const long long nx = (long long)M * K;
    convert_x_kernel<<<(int)(nx / 2048), 256, 0, stream>>>(x, xb, nx);
    dequant_kernel<<<dim3(N / 64, K / 256), 256, 0, stream>>>(qw, scales, zps, deqT, N, K);
    gemm_bf16_bt<<<dim3(N / BN, M / BM), 256, 0, stream>>>(xb, deqT, bias, out, M, N, K);
}

// Round 2
// 176.803 us; speedup vs baseline: 1.0769x; 1.0769x over previous
//
#include <hip/hip_runtime.h>
#include <cstdint>
#include <cstddef>

typedef __attribute__((ext_vector_type(8))) short short8;
typedef __attribute__((ext_vector_type(4))) float floatx4;

typedef __attribute__((address_space(1))) const void gvoid_t;
typedef __attribute__((address_space(3))) void lvoid_t;

// fp32 -> bf16 with round-to-nearest-even (bit pattern as short)
__device__ inline short f2bf(float f) {
    unsigned u = __float_as_uint(f);
    u = (u + 0x7FFFu + ((u >> 16) & 1u)) >> 16;
    return (short)u;
}

// ---------------------------------------------------------------------------
// Kernel 1: convert x (fp32 [M][K]) -> bf16 [M][K] in workspace
// ---------------------------------------------------------------------------
__global__ __launch_bounds__(256) void convert_x_kernel(
    const float* __restrict__ x, short* __restrict__ xb, long long n)
{
    long long i = ((long long)blockIdx.x * 256 + threadIdx.x) * 8;
    if (i + 8 > n) return;
    const float4* p = (const float4*)(x + i);
    float4 v0 = p[0];
    float4 v1 = p[1];
    short8 h;
    h[0] = f2bf(v0.x); h[1] = f2bf(v0.y); h[2] = f2bf(v0.z); h[3] = f2bf(v0.w);
    h[4] = f2bf(v1.x); h[5] = f2bf(v1.y); h[6] = f2bf(v1.z); h[7] = f2bf(v1.w);
    *(short8*)(xb + i) = h;
}

// ---------------------------------------------------------------------------
// Kernel 2: dequantize qweight (int32 [K/8][N], 8x4-bit packed along K) into
// transposed bf16 deqT [N][K].
// Tile: 32 qweight rows (256 k) x 64 n per block.
// Phase 1: coalesced global->LDS (pad 65).
// Phase 2 (R2 fix): wave-iteration = 2 n-rows x 256 k; lanes 0-31 write row
// 2p (512B contiguous), lanes 32-63 write row 2p+1 -> 1KB/wave coalesced
// stores (prev version scattered 16B/lane over 16 rows: 64 txn/store, ~4x
// write cost -> the 94us prologue).
// LDS read addr = rq*65 + n : banks (rq+n)%32 -> 32 distinct, 2-way over the
// full wave = free (m136).
// ---------------------------------------------------------------------------
__global__ __launch_bounds__(256) void dequant_kernel(
    const int* __restrict__ qw, const float* __restrict__ scales,
    const float* __restrict__ zps, short* __restrict__ deqT,
    int N, int K)
{
    __shared__ int lds_q[32 * 65];
    const int t  = threadIdx.x;
    const int n0 = blockIdx.x * 64;
    const int r0 = blockIdx.y * 32;   // qweight row tile (32 rows = 256 k)

    // Phase 1: coalesced load of the 32x64 int32 tile into LDS (pad 65)
    #pragma unroll
    for (int v = 0; v < 2; ++v) {
        int idx = t + v * 256;            // 0..511 int4-chunks
        int row = idx >> 4;               // 16 int4 per 64-col row
        int c4  = (idx & 15) * 4;
        const int4 q4 = *(const int4*)(qw + (size_t)(r0 + row) * N + n0 + c4);
        int base = row * 65 + c4;
        lds_q[base + 0] = q4.x;
        lds_q[base + 1] = q4.y;
        lds_q[base + 2] = q4.z;
        lds_q[base + 3] = q4.w;
    }
    __syncthreads();

    const int L  = t & 63;
    const int w  = t >> 6;
    const int rq = L & 31;            // qw row this lane unpacks (256 k / 8)
    const int hi = L >> 5;            // 0: row 2p, 1: row 2p+1
    const int g  = (r0 + rq) >> 4;    // quant group of this lane's 8 k-values

    #pragma unroll
    for (int it = 0; it < 8; ++it) {
        const int p  = w * 8 + it;    // row-pair index 0..31
        const int nl = 2 * p + hi;    // local n row 0..63

        float s = scales[(size_t)g * N + n0 + nl];
        s = fminf(fmaxf(s, 1e-5f), 1e4f);
        float z = rintf(zps[(size_t)g * N + n0 + nl]);
        z = fminf(fmaxf(z, 0.0f), 15.0f);

        const int q = lds_q[rq * 65 + nl];
        short8 h;
        #pragma unroll
        for (int j = 0; j < 8; ++j) {
            float f = (float)((q >> (4 * j)) & 15);
            h[j] = f2bf((f - z) * s);
        }
        // lanes 0-31: 512B contiguous (row 2p), lanes 32-63: row 2p+1
        *(short8*)(deqT + (size_t)(n0 + nl) * K + (size_t)(r0 + rq) * 8) = h;
    }
}

// ---------------------------------------------------------------------------
// Kernel 3: bf16 GEMM, C = A[M][K] * Bt[N][K]^T + bias, fp32 out.
// m97 structure: 128x128 tile, BK=64, global_load_lds(16B) staging,
// 4 waves each computing 64x64 via 4x4 grid of 16x16x32 MFMA.
// XOR chunk swizzle: LDS position p of row m holds global chunk p^(m&7),
// so fragment ds_read_b128s spread over all 32 banks (2-way only —
// confirmed SQ_LDS_BANK_CONFLICT = 0 in R1).
// ---------------------------------------------------------------------------
#define BM 128
#define BN 128
#define BK 64

__global__ __launch_bounds__(256) void gemm_bf16_bt(
    const short* __restrict__ A, const short* __restrict__ Bt,
    const float* __restrict__ bias, float* __restrict__ C,
    int M, int N, int K)
{
    __shared__ __align__(16) short a_lds[BM * BK];
    __shared__ __align__(16) short b_lds[BN * BK];

    const int t  = threadIdx.x;
    const int L  = t & 63;
    const int w  = t >> 6;
    const int m0 = blockIdx.y * BM;
    const int n0 = blockIdx.x * BN;
    const int wm = (w & 1) * 64;
    const int wn = (w >> 1) * 64;

    floatx4 acc[4][4] = {};

    // staging: per inst i, wave w covers rows i*32 + w*8 + (L>>3);
    // LDS slot = uniform base + lane*16B  (hardware-enforced order)
    const int sr = L >> 3;           // row within the wave's 8-row chunk
    const int sc = L & 7;            // LDS 16B-chunk position within row
    const int gc = sc ^ sr;          // swizzled global chunk ((row&7)==sr)
    const short* ag = A  + (size_t)(m0 + w * 8 + sr) * K + gc * 8;
    const short* bg = Bt + (size_t)(n0 + w * 8 + sr) * K + gc * 8;
    short* a_dst = a_lds + (w * 8) * BK;
    short* b_dst = b_lds + (w * 8) * BK;

    for (int kt = 0; kt < K; kt += BK) {
        #pragma unroll
        for (int i = 0; i < 4; ++i) {
            __builtin_amdgcn_global_load_lds(
                (gvoid_t*)(ag + (size_t)i * 32 * K + kt),
                (lvoid_t*)(a_dst + i * 32 * BK), 16, 0, 0);
            __builtin_amdgcn_global_load_lds(
                (gvoid_t*)(bg + (size_t)i * 32 * K + kt),
                (lvoid_t*)(b_dst + i * 32 * BK), 16, 0, 0);
        }
        __syncthreads();

        #pragma unroll
        for (int s = 0; s < 2; ++s) {
            const int p = ((s * 4) + (L >> 4)) ^ (L & 7);  // swizzled LDS chunk
            short8 af[4], bfr[4];
            #pragma unroll
            for (int i = 0; i < 4; ++i)
                af[i] = *(const short8*)(a_lds + (wm + 16 * i + (L & 15)) * BK + p * 8);
            #pragma unroll
            for (int j = 0; j < 4; ++j)
                bfr[j] = *(const short8*)(b_lds + (wn + 16 * j + (L & 15)) * BK + p * 8);
            #pragma unroll
            for (int i = 0; i < 4; ++i) {
                #pragma unroll
                for (int j = 0; j < 4; ++j)
                    acc[i][j] = __builtin_amdgcn_mfma_f32_16x16x32_bf16(
                        af[i], bfr[j], acc[i][j], 0, 0, 0);
            }
        }
        __syncthreads();
    }

    // Epilogue: C/D layout col = lane&15, row = (lane>>4)*4 + reg  (m89/m91)
    float bv[4];
    #pragma unroll
    for (int j = 0; j < 4; ++j)
        bv[j] = bias[n0 + wn + 16 * j + (L & 15)];
    const int col0 = n0 + wn + (L & 15);
    #pragma unroll
    for (int i = 0; i < 4; ++i) {
        const int row0 = m0 + wm + 16 * i + (L >> 4) * 4;
        #pragma unroll
        for (int r = 0; r < 4; ++r) {
            float* outr = C + (size_t)(row0 + r) * N + col0;
            #pragma unroll
            for (int j = 0; j < 4; ++j)
                outr[16 * j] = acc[i][j][r] + bv[j];
        }
    }
}

// ---------------------------------------------------------------------------
extern "C" void kernel_launch(void* const* d_in, const int* in_sizes, int n_in,
                              void* d_out, int out_size, void* d_ws, size_t ws_size,
                              hipStream_t stream)
{
    const float* x      = (const float*)d_in[0];
    const float* scales = (const float*)d_in[1];
    const float* zps    = (const float*)d_in[2];
    const float* bias   = (const float*)d_in[3];
    const int*   qw     = (const int*)d_in[4];

    const int N = in_sizes[3];          // outfeatures (bias length)
    const int G = in_sizes[1] / N;      // num groups
    const int K = G * 128;              // infeatures
    const int M = in_sizes[0] / K;      // tokens

    short* xb   = (short*)d_ws;                       // M*K bf16
    short* deqT = xb + (size_t)M * K;                 // N*K bf16
    float* out  = (float*)d_out;

    const long long nx = (long long)M * K;
    convert_x_kernel<<<(int)(nx / 2048), 256, 0, stream>>>(x, xb, nx);
    dequant_kernel<<<dim3(N / 64, K / 256), 256, 0, stream>>>(qw, scales, zps, deqT, N, K);
    gemm_bf16_bt<<<dim3(N / BN, M / BM), 256, 0, stream>>>(xb, deqT, bias, out, M, N, K);
}

// Round 3
// 167.756 us; speedup vs baseline: 1.1349x; 1.0539x over previous
//
#include <hip/hip_runtime.h>
#include <cstdint>
#include <cstddef>

typedef __attribute__((ext_vector_type(8))) short short8;
typedef __attribute__((ext_vector_type(4))) float floatx4;

typedef __attribute__((address_space(1))) const void gvoid_t;
typedef __attribute__((address_space(3))) void lvoid_t;

// fp32 -> bf16 with round-to-nearest-even (bit pattern as short)
__device__ inline short f2bf(float f) {
    unsigned u = __float_as_uint(f);
    u = (u + 0x7FFFu + ((u >> 16) & 1u)) >> 16;
    return (short)u;
}

// ---------------------------------------------------------------------------
// Kernel 1: convert x (fp32 [M][K]) -> bf16 [M][K] in workspace
// ---------------------------------------------------------------------------
__global__ __launch_bounds__(256) void convert_x_kernel(
    const float* __restrict__ x, short* __restrict__ xb, long long n)
{
    long long i = ((long long)blockIdx.x * 256 + threadIdx.x) * 8;
    if (i + 8 > n) return;
    const float4* p = (const float4*)(x + i);
    float4 v0 = p[0];
    float4 v1 = p[1];
    short8 h;
    h[0] = f2bf(v0.x); h[1] = f2bf(v0.y); h[2] = f2bf(v0.z); h[3] = f2bf(v0.w);
    h[4] = f2bf(v1.x); h[5] = f2bf(v1.y); h[6] = f2bf(v1.z); h[7] = f2bf(v1.w);
    *(short8*)(xb + i) = h;
}

// ---------------------------------------------------------------------------
// Kernel 2: dequantize qweight (int32 [K/8][N], 8x4-bit packed along K) into
// transposed bf16 deqT [N][K].  (R2 coalesced-write version — near roofline:
// R1->R2 total delta matched the predicted write-cost fix.)
// ---------------------------------------------------------------------------
__global__ __launch_bounds__(256) void dequant_kernel(
    const int* __restrict__ qw, const float* __restrict__ scales,
    const float* __restrict__ zps, short* __restrict__ deqT,
    int N, int K)
{
    __shared__ int lds_q[32 * 65];
    const int t  = threadIdx.x;
    const int n0 = blockIdx.x * 64;
    const int r0 = blockIdx.y * 32;   // qweight row tile (32 rows = 256 k)

    // Phase 1: coalesced load of the 32x64 int32 tile into LDS (pad 65)
    #pragma unroll
    for (int v = 0; v < 2; ++v) {
        int idx = t + v * 256;            // 0..511 int4-chunks
        int row = idx >> 4;               // 16 int4 per 64-col row
        int c4  = (idx & 15) * 4;
        const int4 q4 = *(const int4*)(qw + (size_t)(r0 + row) * N + n0 + c4);
        int base = row * 65 + c4;
        lds_q[base + 0] = q4.x;
        lds_q[base + 1] = q4.y;
        lds_q[base + 2] = q4.z;
        lds_q[base + 3] = q4.w;
    }
    __syncthreads();

    const int L  = t & 63;
    const int w  = t >> 6;
    const int rq = L & 31;            // qw row this lane unpacks (256 k / 8)
    const int hi = L >> 5;            // 0: row 2p, 1: row 2p+1
    const int g  = (r0 + rq) >> 4;    // quant group of this lane's 8 k-values

    #pragma unroll
    for (int it = 0; it < 8; ++it) {
        const int p  = w * 8 + it;    // row-pair index 0..31
        const int nl = 2 * p + hi;    // local n row 0..63

        float s = scales[(size_t)g * N + n0 + nl];
        s = fminf(fmaxf(s, 1e-5f), 1e4f);
        float z = rintf(zps[(size_t)g * N + n0 + nl]);
        z = fminf(fmaxf(z, 0.0f), 15.0f);

        const int q = lds_q[rq * 65 + nl];
        short8 h;
        #pragma unroll
        for (int j = 0; j < 8; ++j) {
            float f = (float)((q >> (4 * j)) & 15);
            h[j] = f2bf((f - z) * s);
        }
        // lanes 0-31: 512B contiguous (row 2p), lanes 32-63: row 2p+1
        *(short8*)(deqT + (size_t)(n0 + nl) * K + (size_t)(r0 + rq) * 8) = h;
    }
}

// ---------------------------------------------------------------------------
// Kernel 3: bf16 GEMM, C = A[M][K] * Bt[N][K]^T + bias, fp32 out.
// R3: BK=128 (was 64). Grid is 512 blocks = 2/CU (grid-limited), so the
// 64 KB LDS does NOT cost residency (m132's regression was 3->2 blocks/CU;
// we're already at 2). Barriers halve: 64 K-iters -> 32, with 64 MFMA/wave
// between barriers instead of 32 -> amortizes the vmcnt(0) barrier drain.
// Swizzle (BK=128, 16 chunks/row): LDS pos sc of row r holds global chunk
// sc ^ ((r&3)<<2); read pos p = (s*4 + (L>>4)) ^ ((L&3)<<2). Same
// 8-lanes-per-4-bank-group aliasing class as R1/R2 (measured 0 conflicts).
// ---------------------------------------------------------------------------
#define BM 128
#define BN 128
#define BK 128

__global__ __launch_bounds__(256) void gemm_bf16_bt(
    const short* __restrict__ A, const short* __restrict__ Bt,
    const float* __restrict__ bias, float* __restrict__ C,
    int M, int N, int K)
{
    __shared__ __align__(16) short a_lds[BM * BK];   // 32 KB
    __shared__ __align__(16) short b_lds[BN * BK];   // 32 KB

    const int t  = threadIdx.x;
    const int L  = t & 63;
    const int w  = t >> 6;
    const int m0 = blockIdx.y * BM;
    const int n0 = blockIdx.x * BN;
    const int wm = (w & 1) * 64;
    const int wn = (w >> 1) * 64;

    floatx4 acc[4][4] = {};

    // staging: per inst i, wave w covers rows i*16 + w*4 + (L>>4);
    // LDS slot = uniform base + lane*16B (hardware-enforced order).
    const int sr = L >> 4;            // row within the wave's 4-row window
    const int sc = L & 15;            // 16B-chunk position within row (0..15)
    const int gc = sc ^ (sr << 2);    // swizzled global chunk ((row&3)==sr)
    const short* ag = A  + (size_t)(m0 + w * 4 + sr) * K + gc * 8;
    const short* bg = Bt + (size_t)(n0 + w * 4 + sr) * K + gc * 8;
    short* a_dst = a_lds + (w * 4) * BK;
    short* b_dst = b_lds + (w * 4) * BK;

    for (int kt = 0; kt < K; kt += BK) {
        #pragma unroll
        for (int i = 0; i < 8; ++i) {
            __builtin_amdgcn_global_load_lds(
                (gvoid_t*)(ag + (size_t)i * 16 * K + kt),
                (lvoid_t*)(a_dst + i * 16 * BK), 16, 0, 0);
            __builtin_amdgcn_global_load_lds(
                (gvoid_t*)(bg + (size_t)i * 16 * K + kt),
                (lvoid_t*)(b_dst + i * 16 * BK), 16, 0, 0);
        }
        __syncthreads();

        #pragma unroll
        for (int s = 0; s < 4; ++s) {
            const int p = (s * 4 + (L >> 4)) ^ ((L & 3) << 2);  // swizzled LDS chunk
            short8 af[4], bfr[4];
            #pragma unroll
            for (int i = 0; i < 4; ++i)
                af[i] = *(const short8*)(a_lds + (wm + 16 * i + (L & 15)) * BK + p * 8);
            #pragma unroll
            for (int j = 0; j < 4; ++j)
                bfr[j] = *(const short8*)(b_lds + (wn + 16 * j + (L & 15)) * BK + p * 8);
            #pragma unroll
            for (int i = 0; i < 4; ++i) {
                #pragma unroll
                for (int j = 0; j < 4; ++j)
                    acc[i][j] = __builtin_amdgcn_mfma_f32_16x16x32_bf16(
                        af[i], bfr[j], acc[i][j], 0, 0, 0);
            }
        }
        __syncthreads();
    }

    // Epilogue: C/D layout col = lane&15, row = (lane>>4)*4 + reg  (m89/m91)
    float bv[4];
    #pragma unroll
    for (int j = 0; j < 4; ++j)
        bv[j] = bias[n0 + wn + 16 * j + (L & 15)];
    const int col0 = n0 + wn + (L & 15);
    #pragma unroll
    for (int i = 0; i < 4; ++i) {
        const int row0 = m0 + wm + 16 * i + (L >> 4) * 4;
        #pragma unroll
        for (int r = 0; r < 4; ++r) {
            float* outr = C + (size_t)(row0 + r) * N + col0;
            #pragma unroll
            for (int j = 0; j < 4; ++j)
                outr[16 * j] = acc[i][j][r] + bv[j];
        }
    }
}

// ---------------------------------------------------------------------------
extern "C" void kernel_launch(void* const* d_in, const int* in_sizes, int n_in,
                              void* d_out, int out_size, void* d_ws, size_t ws_size,
                              hipStream_t stream)
{
    const float* x      = (const float*)d_in[0];
    const float* scales = (const float*)d_in[1];
    const float* zps    = (const float*)d_in[2];
    const float* bias   = (const float*)d_in[3];
    const int*   qw     = (const int*)d_in[4];

    const int N = in_sizes[3];          // outfeatures (bias length)
    const int G = in_sizes[1] / N;      // num groups
    const int K = G * 128;              // infeatures
    const int M = in_sizes[0] / K;      // tokens

    short* xb   = (short*)d_ws;                       // M*K bf16
    short* deqT = xb + (size_t)M * K;                 // N*K bf16
    float* out  = (float*)d_out;

    const long long nx = (long long)M * K;
    convert_x_kernel<<<(int)(nx / 2048), 256, 0, stream>>>(x, xb, nx);
    dequant_kernel<<<dim3(N / 64, K / 256), 256, 0, stream>>>(qw, scales, zps, deqT, N, K);
    gemm_bf16_bt<<<dim3(N / BN, M / BM), 256, 0, stream>>>(xb, deqT, bias, out, M, N, K);
}

// Round 4
// 167.289 us; speedup vs baseline: 1.1381x; 1.0028x over previous
//
#include <hip/hip_runtime.h>
#include <cstdint>
#include <cstddef>

typedef __attribute__((ext_vector_type(8))) short short8;
typedef __attribute__((ext_vector_type(4))) float floatx4;

typedef __attribute__((address_space(1))) const void gvoid_t;
typedef __attribute__((address_space(3))) void lvoid_t;

// fp32 -> bf16 with round-to-nearest-even (bit pattern as short)
__device__ inline short f2bf(float f) {
    unsigned u = __float_as_uint(f);
    u = (u + 0x7FFFu + ((u >> 16) & 1u)) >> 16;
    return (short)u;
}

// ---------------------------------------------------------------------------
// Kernel 1: convert x (fp32 [M][K]) -> bf16 [M][K] in workspace
// ---------------------------------------------------------------------------
__global__ __launch_bounds__(256) void convert_x_kernel(
    const float* __restrict__ x, short* __restrict__ xb, long long n)
{
    long long i = ((long long)blockIdx.x * 256 + threadIdx.x) * 8;
    if (i + 8 > n) return;
    const float4* p = (const float4*)(x + i);
    float4 v0 = p[0];
    float4 v1 = p[1];
    short8 h;
    h[0] = f2bf(v0.x); h[1] = f2bf(v0.y); h[2] = f2bf(v0.z); h[3] = f2bf(v0.w);
    h[4] = f2bf(v1.x); h[5] = f2bf(v1.y); h[6] = f2bf(v1.z); h[7] = f2bf(v1.w);
    *(short8*)(xb + i) = h;
}

// ---------------------------------------------------------------------------
// Kernel 2: dequantize qweight (int32 [K/8][N], 8x4-bit packed along K) into
// transposed bf16 deqT [N][K].  (R2 coalesced-write version — near roofline.)
// ---------------------------------------------------------------------------
__global__ __launch_bounds__(256) void dequant_kernel(
    const int* __restrict__ qw, const float* __restrict__ scales,
    const float* __restrict__ zps, short* __restrict__ deqT,
    int N, int K)
{
    __shared__ int lds_q[32 * 65];
    const int t  = threadIdx.x;
    const int n0 = blockIdx.x * 64;
    const int r0 = blockIdx.y * 32;   // qweight row tile (32 rows = 256 k)

    // Phase 1: coalesced load of the 32x64 int32 tile into LDS (pad 65)
    #pragma unroll
    for (int v = 0; v < 2; ++v) {
        int idx = t + v * 256;            // 0..511 int4-chunks
        int row = idx >> 4;               // 16 int4 per 64-col row
        int c4  = (idx & 15) * 4;
        const int4 q4 = *(const int4*)(qw + (size_t)(r0 + row) * N + n0 + c4);
        int base = row * 65 + c4;
        lds_q[base + 0] = q4.x;
        lds_q[base + 1] = q4.y;
        lds_q[base + 2] = q4.z;
        lds_q[base + 3] = q4.w;
    }
    __syncthreads();

    const int L  = t & 63;
    const int w  = t >> 6;
    const int rq = L & 31;            // qw row this lane unpacks (256 k / 8)
    const int hi = L >> 5;            // 0: row 2p, 1: row 2p+1
    const int g  = (r0 + rq) >> 4;    // quant group of this lane's 8 k-values

    #pragma unroll
    for (int it = 0; it < 8; ++it) {
        const int p  = w * 8 + it;    // row-pair index 0..31
        const int nl = 2 * p + hi;    // local n row 0..63

        float s = scales[(size_t)g * N + n0 + nl];
        s = fminf(fmaxf(s, 1e-5f), 1e4f);
        float z = rintf(zps[(size_t)g * N + n0 + nl]);
        z = fminf(fmaxf(z, 0.0f), 15.0f);

        const int q = lds_q[rq * 65 + nl];
        short8 h;
        #pragma unroll
        for (int j = 0; j < 8; ++j) {
            float f = (float)((q >> (4 * j)) & 15);
            h[j] = f2bf((f - z) * s);
        }
        // lanes 0-31: 512B contiguous (row 2p), lanes 32-63: row 2p+1
        *(short8*)(deqT + (size_t)(n0 + nl) * K + (size_t)(r0 + rq) * 8) = h;
    }
}

// ---------------------------------------------------------------------------
// Kernel 3: bf16 GEMM, C = A[M][K] * Bt[N][K]^T + bias, fp32 out.
// BK=128, grid 512 blocks = 2/CU (grid-limited), 64 KB LDS free of
// residency cost. R4 swizzle fix: with BK=128 the row stride is 256B = 0
// mod 32 banks, so bank = (p%8)*4 depends ONLY on low 3 bits of chunk pos.
// R3's key ((r&3)<<2) left p%8 with 2 values per quarter-wave -> 8-way
// conflicts (8.39M cycles measured). New key = r&7 (3 low bits): stage
// global chunk sc ^ (r&7) at pos sc; read p = (s*4+(L>>4)) ^ (L&7).
// Per 16-lane quarter p%8 covers 0..7 twice -> 32 banks 2-way = free.
// ---------------------------------------------------------------------------
#define BM 128
#define BN 128
#define BK 128

__global__ __launch_bounds__(256) void gemm_bf16_bt(
    const short* __restrict__ A, const short* __restrict__ Bt,
    const float* __restrict__ bias, float* __restrict__ C,
    int M, int N, int K)
{
    __shared__ __align__(16) short a_lds[BM * BK];   // 32 KB
    __shared__ __align__(16) short b_lds[BN * BK];   // 32 KB

    const int t  = threadIdx.x;
    const int L  = t & 63;
    const int w  = t >> 6;
    const int m0 = blockIdx.y * BM;
    const int n0 = blockIdx.x * BN;
    const int wm = (w & 1) * 64;
    const int wn = (w >> 1) * 64;

    floatx4 acc[4][4] = {};

    // staging: per inst i, wave w covers rows w*4 + 16*i + (L>>4);
    // LDS slot = uniform base + lane*16B (hardware-enforced order).
    const int sr  = L >> 4;           // row within the wave's 4-row window
    const int sc  = L & 15;           // 16B-chunk position within row (0..15)
    const int key = ((w & 1) << 2) | sr;   // = row & 7 (invariant in i)
    const int gc  = sc ^ key;         // global chunk staged at LDS pos sc
    const short* ag = A  + (size_t)(m0 + w * 4 + sr) * K + gc * 8;
    const short* bg = Bt + (size_t)(n0 + w * 4 + sr) * K + gc * 8;
    short* a_dst = a_lds + (w * 4) * BK;
    short* b_dst = b_lds + (w * 4) * BK;

    for (int kt = 0; kt < K; kt += BK) {
        #pragma unroll
        for (int i = 0; i < 8; ++i) {
            __builtin_amdgcn_global_load_lds(
                (gvoid_t*)(ag + (size_t)i * 16 * K + kt),
                (lvoid_t*)(a_dst + i * 16 * BK), 16, 0, 0);
            __builtin_amdgcn_global_load_lds(
                (gvoid_t*)(bg + (size_t)i * 16 * K + kt),
                (lvoid_t*)(b_dst + i * 16 * BK), 16, 0, 0);
        }
        __syncthreads();

        #pragma unroll
        for (int s = 0; s < 4; ++s) {
            // global chunk c = s*4 + (L>>4) of row r (r&7 == L&7):
            const int p = (s * 4 + (L >> 4)) ^ (L & 7);  // swizzled LDS pos
            short8 af[4], bfr[4];
            #pragma unroll
            for (int i = 0; i < 4; ++i)
                af[i] = *(const short8*)(a_lds + (wm + 16 * i + (L & 15)) * BK + p * 8);
            #pragma unroll
            for (int j = 0; j < 4; ++j)
                bfr[j] = *(const short8*)(b_lds + (wn + 16 * j + (L & 15)) * BK + p * 8);
            #pragma unroll
            for (int i = 0; i < 4; ++i) {
                #pragma unroll
                for (int j = 0; j < 4; ++j)
                    acc[i][j] = __builtin_amdgcn_mfma_f32_16x16x32_bf16(
                        af[i], bfr[j], acc[i][j], 0, 0, 0);
            }
        }
        __syncthreads();
    }

    // Epilogue: C/D layout col = lane&15, row = (lane>>4)*4 + reg  (m89/m91)
    float bv[4];
    #pragma unroll
    for (int j = 0; j < 4; ++j)
        bv[j] = bias[n0 + wn + 16 * j + (L & 15)];
    const int col0 = n0 + wn + (L & 15);
    #pragma unroll
    for (int i = 0; i < 4; ++i) {
        const int row0 = m0 + wm + 16 * i + (L >> 4) * 4;
        #pragma unroll
        for (int r = 0; r < 4; ++r) {
            float* outr = C + (size_t)(row0 + r) * N + col0;
            #pragma unroll
            for (int j = 0; j < 4; ++j)
                outr[16 * j] = acc[i][j][r] + bv[j];
        }
    }
}

// ---------------------------------------------------------------------------
extern "C" void kernel_launch(void* const* d_in, const int* in_sizes, int n_in,
                              void* d_out, int out_size, void* d_ws, size_t ws_size,
                              hipStream_t stream)
{
    const float* x      = (const float*)d_in[0];
    const float* scales = (const float*)d_in[1];
    const float* zps    = (const float*)d_in[2];
    const float* bias   = (const float*)d_in[3];
    const int*   qw     = (const int*)d_in[4];

    const int N = in_sizes[3];          // outfeatures (bias length)
    const int G = in_sizes[1] / N;      // num groups
    const int K = G * 128;              // infeatures
    const int M = in_sizes[0] / K;      // tokens

    short* xb   = (short*)d_ws;                       // M*K bf16
    short* deqT = xb + (size_t)M * K;                 // N*K bf16
    float* out  = (float*)d_out;

    const long long nx = (long long)M * K;
    convert_x_kernel<<<(int)(nx / 2048), 256, 0, stream>>>(x, xb, nx);
    dequant_kernel<<<dim3(N / 64, K / 256), 256, 0, stream>>>(qw, scales, zps, deqT, N, K);
    gemm_bf16_bt<<<dim3(N / BN, M / BM), 256, 0, stream>>>(xb, deqT, bias, out, M, N, K);
}

// Round 5
// 166.879 us; speedup vs baseline: 1.1409x; 1.0025x over previous
//
#include <hip/hip_runtime.h>
#include <cstdint>
#include <cstddef>

typedef __attribute__((ext_vector_type(8))) short short8;
typedef __attribute__((ext_vector_type(4))) float floatx4;

typedef __attribute__((address_space(1))) const void gvoid_t;
typedef __attribute__((address_space(3))) void lvoid_t;

// fp32 -> bf16 with round-to-nearest-even (bit pattern as short)
__device__ inline short f2bf(float f) {
    unsigned u = __float_as_uint(f);
    u = (u + 0x7FFFu + ((u >> 16) & 1u)) >> 16;
    return (short)u;
}

// ---------------------------------------------------------------------------
// Merged prologue: blocks [0,ncvt) convert x fp32->bf16; blocks [ncvt,..)
// dequantize qweight into transposed bf16 deqT [N][K]. Both memory-bound;
// merging saves one graph-node launch gap. Bodies identical to R2/R4
// versions (dequant measured near its 40MB-traffic roofline).
// ---------------------------------------------------------------------------
__global__ __launch_bounds__(256) void prologue_kernel(
    const float* __restrict__ x, short* __restrict__ xb, long long nx, int ncvt,
    const int* __restrict__ qw, const float* __restrict__ scales,
    const float* __restrict__ zps, short* __restrict__ deqT,
    int N, int K, int nbx)
{
    __shared__ int lds_q[32 * 65];
    const int t = threadIdx.x;

    if ((int)blockIdx.x < ncvt) {
        // ---- convert x ----
        long long i = ((long long)blockIdx.x * 256 + t) * 8;
        if (i + 8 > nx) return;
        const float4* p = (const float4*)(x + i);
        float4 v0 = p[0];
        float4 v1 = p[1];
        short8 h;
        h[0] = f2bf(v0.x); h[1] = f2bf(v0.y); h[2] = f2bf(v0.z); h[3] = f2bf(v0.w);
        h[4] = f2bf(v1.x); h[5] = f2bf(v1.y); h[6] = f2bf(v1.z); h[7] = f2bf(v1.w);
        *(short8*)(xb + i) = h;
        return;
    }

    // ---- dequant ----
    const int b2 = (int)blockIdx.x - ncvt;
    const int n0 = (b2 % nbx) * 64;
    const int r0 = (b2 / nbx) * 32;   // qweight row tile (32 rows = 256 k)

    // Phase 1: coalesced load of the 32x64 int32 tile into LDS (pad 65)
    #pragma unroll
    for (int v = 0; v < 2; ++v) {
        int idx = t + v * 256;            // 0..511 int4-chunks
        int row = idx >> 4;               // 16 int4 per 64-col row
        int c4  = (idx & 15) * 4;
        const int4 q4 = *(const int4*)(qw + (size_t)(r0 + row) * N + n0 + c4);
        int base = row * 65 + c4;
        lds_q[base + 0] = q4.x;
        lds_q[base + 1] = q4.y;
        lds_q[base + 2] = q4.z;
        lds_q[base + 3] = q4.w;
    }
    __syncthreads();

    const int L  = t & 63;
    const int w  = t >> 6;
    const int rq = L & 31;            // qw row this lane unpacks
    const int hi = L >> 5;            // 0: row 2p, 1: row 2p+1
    const int g  = (r0 + rq) >> 4;    // quant group of this lane's 8 k-values

    #pragma unroll
    for (int it = 0; it < 8; ++it) {
        const int p  = w * 8 + it;    // row-pair index 0..31
        const int nl = 2 * p + hi;    // local n row 0..63

        float s = scales[(size_t)g * N + n0 + nl];
        s = fminf(fmaxf(s, 1e-5f), 1e4f);
        float z = rintf(zps[(size_t)g * N + n0 + nl]);
        z = fminf(fmaxf(z, 0.0f), 15.0f);

        const int q = lds_q[rq * 65 + nl];
        short8 h;
        #pragma unroll
        for (int j = 0; j < 8; ++j) {
            float f = (float)((q >> (4 * j)) & 15);
            h[j] = f2bf((f - z) * s);
        }
        // lanes 0-31: 512B contiguous (row 2p), lanes 32-63: row 2p+1
        *(short8*)(deqT + (size_t)(n0 + nl) * K + (size_t)(r0 + rq) * 8) = h;
    }
}

// ---------------------------------------------------------------------------
// Kernel 2: bf16 GEMM, C = A[M][K] * Bt[N][K]^T + bias, fp32 out.
// R5: single-barrier double-buffered K-loop, BK=64 (2x32KB = 64KB LDS,
// still 2 blocks/CU). Per iter: barrier -> issue next tile's
// global_load_lds into buf^1 -> compute buf. The compiler's vmcnt(0)
// drain before s_barrier then waits on loads issued a full compute phase
// (~300cyc) earlier instead of 0 cycles earlier -> the structural barrier
// stall is amortized. BK=64 layout restores the R1/R2 bank pattern that
// measured SQ_LDS_BANK_CONFLICT = 0 (BK=128 layout had a stubborn 4
// cycles/read = 8.39M that two different swizzle keys could not remove).
// Swizzle: stage global chunk (L&7)^(L>>3) at LDS pos (L&7) (row&7 = L>>3);
// read pos p = (s*4 + (L>>4)) ^ (L&7).
// ---------------------------------------------------------------------------
#define BM 128
#define BN 128
#define BK 64

__global__ __launch_bounds__(256) void gemm_bf16_bt(
    const short* __restrict__ A, const short* __restrict__ Bt,
    const float* __restrict__ bias, float* __restrict__ C,
    int M, int N, int K)
{
    __shared__ __align__(16) short a_lds[2][BM * BK];   // 2 x 16 KB
    __shared__ __align__(16) short b_lds[2][BN * BK];   // 2 x 16 KB

    const int t  = threadIdx.x;
    const int L  = t & 63;
    const int w  = t >> 6;
    const int m0 = blockIdx.y * BM;
    const int n0 = blockIdx.x * BN;
    const int wm = (w & 1) * 64;
    const int wn = (w >> 1) * 64;

    floatx4 acc[4][4] = {};

    // staging: per inst i, wave w covers rows w*8 + 32*i + (L>>3);
    // LDS slot = uniform base + lane*16B (hardware-enforced order).
    const int sr = L >> 3;            // row within the wave's 8-row window
    const int sc = L & 7;             // 16B-chunk position within row (0..7)
    const int gc = sc ^ sr;           // global chunk staged at LDS pos sc
    const short* ag = A  + (size_t)(m0 + w * 8 + sr) * K + gc * 8;
    const short* bg = Bt + (size_t)(n0 + w * 8 + sr) * K + gc * 8;
    const int dst = (w * 8) * BK;     // wave-uniform offset within buffer

    const int NK = K / BK;

    // prologue: stage tile 0 into buffer 0
    #pragma unroll
    for (int i = 0; i < 4; ++i) {
        __builtin_amdgcn_global_load_lds(
            (gvoid_t*)(ag + (size_t)i * 32 * K),
            (lvoid_t*)(&a_lds[0][dst + i * 32 * BK]), 16, 0, 0);
        __builtin_amdgcn_global_load_lds(
            (gvoid_t*)(bg + (size_t)i * 32 * K),
            (lvoid_t*)(&b_lds[0][dst + i * 32 * BK]), 16, 0, 0);
    }

    for (int ti = 0; ti < NK; ++ti) {
        const int cur = ti & 1;
        // drains cur's loads (in flight for a full compute phase, except ti=0)
        // + guarantees all waves finished reading buf cur^1 (lgkmcnt at barrier)
        __syncthreads();

        if (ti + 1 < NK) {
            const int kn = (ti + 1) * BK;
            #pragma unroll
            for (int i = 0; i < 4; ++i) {
                __builtin_amdgcn_global_load_lds(
                    (gvoid_t*)(ag + (size_t)i * 32 * K + kn),
                    (lvoid_t*)(&a_lds[cur ^ 1][dst + i * 32 * BK]), 16, 0, 0);
                __builtin_amdgcn_global_load_lds(
                    (gvoid_t*)(bg + (size_t)i * 32 * K + kn),
                    (lvoid_t*)(&b_lds[cur ^ 1][dst + i * 32 * BK]), 16, 0, 0);
            }
        }

        #pragma unroll
        for (int s = 0; s < 2; ++s) {
            // global chunk c = s*4 + (L>>4) of row r (r&7 == L&7):
            const int p = (s * 4 + (L >> 4)) ^ (L & 7);  // swizzled LDS pos
            short8 af[4], bfr[4];
            #pragma unroll
            for (int i = 0; i < 4; ++i)
                af[i] = *(const short8*)(&a_lds[cur][(wm + 16 * i + (L & 15)) * BK + p * 8]);
            #pragma unroll
            for (int j = 0; j < 4; ++j)
                bfr[j] = *(const short8*)(&b_lds[cur][(wn + 16 * j + (L & 15)) * BK + p * 8]);
            #pragma unroll
            for (int i = 0; i < 4; ++i) {
                #pragma unroll
                for (int j = 0; j < 4; ++j)
                    acc[i][j] = __builtin_amdgcn_mfma_f32_16x16x32_bf16(
                        af[i], bfr[j], acc[i][j], 0, 0, 0);
            }
        }
    }

    // Epilogue: C/D layout col = lane&15, row = (lane>>4)*4 + reg  (m89/m91)
    float bv[4];
    #pragma unroll
    for (int j = 0; j < 4; ++j)
        bv[j] = bias[n0 + wn + 16 * j + (L & 15)];
    const int col0 = n0 + wn + (L & 15);
    #pragma unroll
    for (int i = 0; i < 4; ++i) {
        const int row0 = m0 + wm + 16 * i + (L >> 4) * 4;
        #pragma unroll
        for (int r = 0; r < 4; ++r) {
            float* outr = C + (size_t)(row0 + r) * N + col0;
            #pragma unroll
            for (int j = 0; j < 4; ++j)
                outr[16 * j] = acc[i][j][r] + bv[j];
        }
    }
}

// ---------------------------------------------------------------------------
extern "C" void kernel_launch(void* const* d_in, const int* in_sizes, int n_in,
                              void* d_out, int out_size, void* d_ws, size_t ws_size,
                              hipStream_t stream)
{
    const float* x      = (const float*)d_in[0];
    const float* scales = (const float*)d_in[1];
    const float* zps    = (const float*)d_in[2];
    const float* bias   = (const float*)d_in[3];
    const int*   qw     = (const int*)d_in[4];

    const int N = in_sizes[3];          // outfeatures (bias length)
    const int G = in_sizes[1] / N;      // num groups
    const int K = G * 128;              // infeatures
    const int M = in_sizes[0] / K;      // tokens

    short* xb   = (short*)d_ws;                       // M*K bf16
    short* deqT = xb + (size_t)M * K;                 // N*K bf16
    float* out  = (float*)d_out;

    const long long nx = (long long)M * K;
    const int ncvt = (int)(nx / 2048);
    const int nbx  = N / 64;
    const int ndq  = nbx * (K / 256);

    prologue_kernel<<<ncvt + ndq, 256, 0, stream>>>(
        x, xb, nx, ncvt, qw, scales, zps, deqT, N, K, nbx);
    gemm_bf16_bt<<<dim3(N / BN, M / BM), 256, 0, stream>>>(xb, deqT, bias, out, M, N, K);
}